// Round 10
// baseline (454.750 us; speedup 1.0000x reference)
//
#include <hip/hip_runtime.h>
#include <hip/hip_bf16.h>
#include <hip/hip_fp16.h>

// GAT, 2 layers. N=50000, F=128, H=4, C=32, E=1.6M (+N self-loops).
// R16 (317.7us, best): aggregate = 1 wave = 1 node x 64 lanes, merged
// h[N][128]bf16, each edge visited once, wave-uniform col/as scalarized
// (SGPR 64). Fused weight math (R13). Aggregate loop is at its local
// optimum (R8-R15 ledger) - DO NOT TOUCH.
// R17: CSR build overhauled. partition+build_bucket (12.8MB ebuf written
// then re-read, shared hists, serial per-bucket scans) replaced by:
// prep_hist += per-node deg via global atomics (200KB, L2-resident, ~32
// ops/counter -> low contention); row_scan (512 blk x 1 wave) turns deg
// into row_ptr/cursor under the existing bucket bases; scatter does
// p=atomicAdd(cursor[dst]), col[p]=src directly. Removes 25.6MB of ebuf
// traffic + one dispatch. Edge order per row stays nondeterministic
// (always was, via build_bucket atomics; absmax 3.9e-3 << 1.1e-2 thr).
// GEMM: split-bf16 MFMA (R5), planar logits epilogue.

#define FDIM 128
#define NHEAD 4
#define NB 512          // dst buckets (node ranges of npb) for scan hierarchy

typedef __attribute__((ext_vector_type(16))) float f32x16;
typedef __attribute__((ext_vector_type(8)))  short s16x8;

__device__ inline unsigned short f2bf(float f) {
    union { float f; unsigned u; } v; v.f = f;
    unsigned r = v.u + 0x7fff + ((v.u >> 16) & 1);   // RNE
    return (unsigned short)(r >> 16);
}
__device__ inline float2 bf2f(unsigned v) {
    union { unsigned u; float f; } a, b;
    a.u = v << 16;            // low half  = feature 2c
    b.u = v & 0xffff0000u;    // high half = feature 2c+1
    return make_float2(a.f, b.f);
}
__device__ inline void splitbf(float f, short* hi, short* lo) {
    unsigned u = __float_as_uint(f);
    float rem = f - __uint_as_float(u & 0xffff0000u);
    *hi = (short)(u >> 16);
    *lo = (short)(__float_as_uint(rem) >> 16);
}

// ---- fused: prep W1/W2 (transpose+split+swizzle) + bucket hist + deg -----
__global__ __launch_bounds__(256) void prep_hist(const float* __restrict__ W1,
                                                 short* __restrict__ B1hi,
                                                 short* __restrict__ B1lo,
                                                 const float* __restrict__ W2,
                                                 short* __restrict__ B2hi,
                                                 short* __restrict__ B2lo,
                                                 const int* __restrict__ dst, int E,
                                                 unsigned long long magic,
                                                 int* __restrict__ bcnt,
                                                 int* __restrict__ deg) {
    __shared__ int sh[NB];
    const int t = threadIdx.x;
    const int b = blockIdx.x;
    if (b < 128) {
        const float* W = (b < 64) ? W1 : W2;
        short* Bhi = (b < 64) ? B1hi : B2hi;
        short* Blo = (b < 64) ? B1lo : B2lo;
        int e = (b & 63) * 256 + t;   // e = k*128 + n
        int k = e >> 7, n = e & 127;
        short hi, lo;
        splitbf(W[e], &hi, &lo);
        int idx = n * 128 + (((k >> 3) ^ (n & 15)) << 3) + (k & 7);
        Bhi[idx] = hi;
        Blo[idx] = lo;
        return;
    }
    for (int i = t; i < NB; i += 256) sh[i] = 0;
    __syncthreads();
    const int stride = (gridDim.x - 128) * 256;
    for (int i = (b - 128) * 256 + t; i < E; i += stride) {
        int d = dst[i];
        atomicAdd(&deg[d], 1);                       // per-node degree
        int bk = (int)(((unsigned long long)(unsigned)d * magic) >> 40);
        atomicAdd(&sh[bk], 1);
    }
    __syncthreads();
    for (int i = t; i < NB; i += 256)
        if (sh[i]) atomicAdd(&bcnt[i], sh[i]);
}

// ---- MFMA GEMM: H[M][128](bf16) = A[M][128](f32) @ W; fused a_s/a_d -----
// a_s/a_d written PLANAR: a_s[q*M + row]
__global__ __launch_bounds__(256) void gemm_mfma(const float* __restrict__ A,
                                                 const short* __restrict__ Bghi,
                                                 const short* __restrict__ Bglo,
                                                 unsigned short* __restrict__ H,
                                                 const float* __restrict__ att_s,
                                                 const float* __restrict__ att_d,
                                                 float* __restrict__ a_s,
                                                 float* __restrict__ a_d, int M) {
    __shared__ short Bsm[2][16384];   // 64 KB: [hi/lo][n*128 + k']
    __shared__ float attsm[256];      // att_s[128], att_d[128]
    const int t = threadIdx.x;
    const int bm = blockIdx.x * 64;

    if (t < 128) attsm[t] = att_s[t];
    else         attsm[t] = att_d[t - 128];

    {   // stage B (pre-swizzled; verbatim 32KB+32KB copy)
        const uint4* ghi = (const uint4*)Bghi;
        const uint4* glo = (const uint4*)Bglo;
        uint4* shi = (uint4*)&Bsm[0][0];
        uint4* slo = (uint4*)&Bsm[1][0];
        #pragma unroll
        for (int i = 0; i < 8; i++) {
            shi[t + i * 256] = ghi[t + i * 256];
            slo[t + i * 256] = glo[t + i * 256];
        }
    }

    const int lane = t & 63;
    const int w = t >> 6;
    const int wr = w >> 1, wc = w & 1;     // wave tile: rows wr*32, cols wc*32
    const int m  = lane & 31, h2 = lane >> 5;
    const int grow = bm + wr * 32 + m;

    // A fragments: 8 k-chunks of 16; lane holds k = 16c + 8*h2 + j (j=0..7)
    s16x8 ahi[8], alo[8];
    {
        const bool ok = grow < M;
        const float* ap = A + (size_t)grow * 128 + 8 * h2;
        #pragma unroll
        for (int c = 0; c < 8; c++) {
            float ff[8];
            if (ok) {
                float4 f0 = *(const float4*)(ap + c * 16);
                float4 f1 = *(const float4*)(ap + c * 16 + 4);
                ff[0]=f0.x; ff[1]=f0.y; ff[2]=f0.z; ff[3]=f0.w;
                ff[4]=f1.x; ff[5]=f1.y; ff[6]=f1.z; ff[7]=f1.w;
            } else {
                #pragma unroll
                for (int j = 0; j < 8; j++) ff[j] = 0.f;
            }
            #pragma unroll
            for (int j = 0; j < 8; j++) {
                short hi, lo;
                splitbf(ff[j], &hi, &lo);
                ahi[c][j] = hi;
                alo[c][j] = lo;
            }
        }
    }
    __syncthreads();

    f32x16 acc[2];
    #pragma unroll
    for (int i = 0; i < 16; i++) { acc[0][i] = 0.f; acc[1][i] = 0.f; }

    #pragma unroll
    for (int ni = 0; ni < 2; ni++) {
        const int n = ni * 64 + wc * 32 + m;     // B col for this lane
        const int nbase = n * 128;
        #pragma unroll
        for (int c = 0; c < 8; c++) {
            int chunk8 = 2 * c + h2;
            int koff = ((chunk8 ^ (n & 15)) << 3);
            s16x8 bhi = *(const s16x8*)&Bsm[0][nbase + koff];
            s16x8 blo = *(const s16x8*)&Bsm[1][nbase + koff];
            acc[ni] = __builtin_amdgcn_mfma_f32_32x32x16_bf16(ahi[c], bhi, acc[ni], 0, 0, 0);
            acc[ni] = __builtin_amdgcn_mfma_f32_32x32x16_bf16(alo[c], bhi, acc[ni], 0, 0, 0);
            acc[ni] = __builtin_amdgcn_mfma_f32_32x32x16_bf16(ahi[c], blo, acc[ni], 0, 0, 0);
        }
    }

    __syncthreads();   // all waves done reading Bsm; reuse as htile
    unsigned short* htile = (unsigned short*)&Bsm[0][0];   // [64][128] bf16
    #pragma unroll
    for (int ni = 0; ni < 2; ni++) {
        const int colg = ni * 64 + wc * 32 + m;
        #pragma unroll
        for (int r = 0; r < 16; r++) {
            int row = wr * 32 + (r & 3) + 8 * (r >> 2) + 4 * h2;  // C/D m74/m101
            htile[row * 128 + colg] = (short)f2bf(acc[ni][r]);
        }
    }
    __syncthreads();

    // copy h tile out (merged [row][128]) + logits: thread = (row r, head q)
    {
        const int r = t >> 2, q = t & 3;
        const int growr = bm + r;
        if (growr < M) {
            uint4 v0 = *(uint4*)&htile[r * 128 + q * 32];
            uint4 v1 = *(uint4*)&htile[r * 128 + q * 32 + 8];
            uint4 v2 = *(uint4*)&htile[r * 128 + q * 32 + 16];
            uint4 v3 = *(uint4*)&htile[r * 128 + q * 32 + 24];
            uint4* hg = (uint4*)(H + (size_t)growr * 128);
            hg[q * 4 + 0] = v0; hg[q * 4 + 1] = v1;
            hg[q * 4 + 2] = v2; hg[q * 4 + 3] = v3;
            unsigned uu[16] = {v0.x, v0.y, v0.z, v0.w, v1.x, v1.y, v1.z, v1.w,
                               v2.x, v2.y, v2.z, v2.w, v3.x, v3.y, v3.z, v3.w};
            float ps = 0.f, pd = 0.f;
            #pragma unroll
            for (int i = 0; i < 16; i++) {
                float2 f = bf2f(uu[i]);
                ps += f.x * attsm[q * 32 + 2 * i]       + f.y * attsm[q * 32 + 2 * i + 1];
                pd += f.x * attsm[128 + q * 32 + 2 * i] + f.y * attsm[128 + q * 32 + 2 * i + 1];
            }
            a_s[(size_t)q * M + growr] = ps;     // planar [head][M]
            a_d[(size_t)q * M + growr] = pd;
        }
    }
}

// ------------------------------ CSR build ---------------------------------
// bucket_scan: exclusive scan of 512 bucket counts -> bbase; row_ptr[N]=E.
__global__ __launch_bounds__(256) void bucket_scan(const int* __restrict__ bcnt,
                                                   int* __restrict__ bbase,
                                                   int* __restrict__ row_ptr,
                                                   int N, int E) {
    __shared__ int wsum[4];
    const int t = threadIdx.x, lane = t & 63, wid = t >> 6;
    int v0 = bcnt[2 * t], v1 = bcnt[2 * t + 1];
    int s = v0 + v1, incl = s;
    #pragma unroll
    for (int o = 1; o < 64; o <<= 1) {
        int u = __shfl_up(incl, o, 64);
        if (lane >= o) incl += u;
    }
    if (lane == 63) wsum[wid] = incl;
    __syncthreads();
    if (t == 0) {
        int a = 0;
        #pragma unroll
        for (int i = 0; i < 4; i++) { int x = wsum[i]; wsum[i] = a; a += x; }
    }
    __syncthreads();
    int excl = wsum[wid] + incl - s;
    bbase[2 * t] = excl;
    bbase[2 * t + 1] = excl + v0;
    if (t == 0) { bbase[NB] = E; row_ptr[N] = E; }
}

// row_scan: per-bucket prefix of deg -> row_ptr + cursor (1 wave/bucket).
__global__ __launch_bounds__(64) void row_scan(const int* __restrict__ deg,
                                               const int* __restrict__ bbase,
                                               int npb, int N,
                                               int* __restrict__ row_ptr,
                                               int* __restrict__ cursor) {
    const int b = blockIdx.x;
    const int lane = threadIdx.x;
    const int node0 = b * npb;
    const int base = bbase[b];
    int run = 0;
    for (int c = 0; c * 64 < npb; c++) {
        int idx = c * 64 + lane;
        int node = node0 + idx;
        bool ok = (idx < npb) && (node < N);
        int v = ok ? deg[node] : 0;
        int incl = v;
        #pragma unroll
        for (int o = 1; o < 64; o <<= 1) {
            int u = __shfl_up(incl, o, 64);
            if (lane >= o) incl += u;
        }
        int excl = incl - v + run;
        if (ok) {
            row_ptr[node] = base + excl;
            cursor[node]  = base + excl;
        }
        run += __shfl(incl, 63, 64);
    }
}

// scatter: direct CSR fill via per-node cursors (no ebuf round trip).
__global__ __launch_bounds__(256) void scatter(const int* __restrict__ src,
                                               const int* __restrict__ dst, int E,
                                               int* __restrict__ cursor,
                                               int* __restrict__ col) {
    const int e0 = blockIdx.x * 4096 + threadIdx.x;
    #pragma unroll
    for (int u = 0; u < 16; u++) {
        int i = e0 + u * 256;
        if (i < E) {
            int d = dst[i];
            int p = atomicAdd(&cursor[d], 1);
            col[p] = src[i];
        }
    }
}

// ------------- gather aggregation: fused softmax-weighted sum per dst ------
// R16 geometry (unchanged): 1 wave = 1 node x 64 lanes; lane li owns feats
// 2li,2li+1 of merged h[N][128]bf16; head hd=li>>4. node wave-uniform ->
// row_ptr/col/as_h scalarized. R13 body: 8-chunk + inline leaky+exp + tail.
__global__ __launch_bounds__(64) void aggregate(const unsigned* __restrict__ h,
                                                const float* __restrict__ a_s,
                                                const float* __restrict__ a_d,
                                                const int* __restrict__ row_ptr,
                                                const int* __restrict__ col,
                                                const float* __restrict__ bias,
                                                float* __restrict__ out,
                                                float* __restrict__ out2,
                                                int n, int do_relu) {
    const int node = blockIdx.x;
    const int li = threadIdx.x;             // feature pair 2li,2li+1
    const int hd = li >> 4;                 // head (32 feats each)
    const float* __restrict__ as_h = a_s + (size_t)hd * n;
    const float adv = a_d[(size_t)hd * n + node];

    // self loop
    float e = as_h[node] + adv;
    e = fmaxf(e, 0.2f * e);
    float den = __expf(e);
    float2 hv = bf2f(h[(size_t)node * 64 + li]);
    float num0 = den * hv.x, num1 = den * hv.y;

    const int beg = row_ptr[node], end = row_ptr[node + 1];
    int j = beg;
    for (; j + 8 <= end; j += 8) {
        int s[8];
        #pragma unroll
        for (int u = 0; u < 8; u++) s[u] = col[j + u];
        unsigned v[8];
        #pragma unroll
        for (int u = 0; u < 8; u++) v[u] = h[(size_t)s[u] * 64 + li];
        float av[8];
        #pragma unroll
        for (int u = 0; u < 8; u++) av[u] = as_h[s[u]];
        #pragma unroll
        for (int u = 0; u < 8; u++) {
            float ee = av[u] + adv;
            ee = fmaxf(ee, 0.2f * ee);
            float wgt = __expf(ee);
            den += wgt;
            float2 f = bf2f(v[u]);
            num0 += wgt * f.x;
            num1 += wgt * f.y;
        }
    }
    for (; j < end; j++) {
        int s = col[j];
        float ee = as_h[s] + adv;
        ee = fmaxf(ee, 0.2f * ee);
        float wgt = __expf(ee);
        den += wgt;
        float2 f = bf2f(h[(size_t)s * 64 + li]);
        num0 += wgt * f.x;
        num1 += wgt * f.y;
    }
    float2 bv = ((const float2*)bias)[li];
    float rd = 1.0f / den;
    float o0 = num0 * rd + bv.x;
    float o1 = num1 * rd + bv.y;
    if (do_relu) { o0 = fmaxf(o0, 0.f); o1 = fmaxf(o1, 0.f); }
    ((float2*)out)[(size_t)node * 64 + li] = make_float2(o0, o1);
    if (out2) ((float2*)out2)[(size_t)node * 64 + li] = make_float2(o0, o1);
}

// ------------------------------- launcher ----------------------------------
extern "C" void kernel_launch(void* const* d_in, const int* in_sizes, int n_in,
                              void* d_out, int out_size, void* d_ws, size_t ws_size,
                              hipStream_t stream) {
    const float* x        = (const float*)d_in[0];
    const int*   edge     = (const int*)d_in[1];
    const float* W1       = (const float*)d_in[2];
    const float* att_s1   = (const float*)d_in[3];
    const float* att_d1   = (const float*)d_in[4];
    const float* b1       = (const float*)d_in[5];
    const float* W2       = (const float*)d_in[6];
    const float* att_s2   = (const float*)d_in[7];
    const float* att_d2   = (const float*)d_in[8];
    const float* b2       = (const float*)d_in[9];
    float* out = (float*)d_out;

    const int N = in_sizes[0] / FDIM;         // 50000
    const int E = in_sizes[1] / 2;            // 1600000
    const int* src = edge;
    const int* dst = edge + E;

    const int npb = (N + NB - 1) / NB;        // 98
    const unsigned long long magic = ((1ull << 40) / (unsigned long long)npb) + 1;

    char* w = (char*)d_ws;
    size_t off = 0;
    auto alloc = [&](size_t bytes) { void* p = w + off; off = (off + bytes + 255) & ~(size_t)255; return p; };
    int*   row_ptr = (int*)alloc((size_t)(N + 1) * 4);
    int*   col     = (int*)alloc((size_t)E * 4);
    int*   bcnt    = (int*)alloc((size_t)NB * 4);
    int*   bbase   = (int*)alloc((size_t)(NB + 1) * 4);
    int*   deg     = (int*)alloc((size_t)N * 4);
    int*   cursor  = (int*)alloc((size_t)N * 4);
    unsigned short* h = (unsigned short*)alloc((size_t)N * FDIM * 2); // merged bf16
    float* hx      = (float*)alloc((size_t)N * FDIM * 4);   // layer-1 out
    float* as1     = (float*)alloc((size_t)NHEAD * N * 4);  // planar [4][N]
    float* ad1     = (float*)alloc((size_t)NHEAD * N * 4);
    float* as2     = (float*)alloc((size_t)NHEAD * N * 4);
    float* ad2     = (float*)alloc((size_t)NHEAD * N * 4);
    short* Bg1hi   = (short*)alloc((size_t)128 * 128 * 2);
    short* Bg1lo   = (short*)alloc((size_t)128 * 128 * 2);
    short* Bg2hi   = (short*)alloc((size_t)128 * 128 * 2);
    short* Bg2lo   = (short*)alloc((size_t)128 * 128 * 2);
    (void)ws_size;

    // ---- CSR build: deg histogram -> bucket scan -> row scan -> scatter ----
    hipMemsetAsync(bcnt, 0, (size_t)NB * 4, stream);
    hipMemsetAsync(deg, 0, (size_t)N * 4, stream);
    prep_hist<<<128 + 1024, 256, 0, stream>>>(W1, Bg1hi, Bg1lo, W2, Bg2hi, Bg2lo,
                                              dst, E, magic, bcnt, deg);
    bucket_scan<<<1, 256, 0, stream>>>(bcnt, bbase, row_ptr, N, E);
    row_scan<<<NB, 64, 0, stream>>>(deg, bbase, npb, N, row_ptr, cursor);
    scatter<<<(E + 4095) / 4096, 256, 0, stream>>>(src, dst, E, cursor, col);

    const int gblocks = (N + 63) / 64;

    // ---- layer 1 ----
    gemm_mfma<<<gblocks, 256, 0, stream>>>(x, Bg1hi, Bg1lo, h,
                                           att_s1, att_d1, as1, ad1, N);
    aggregate<<<N, 64, 0, stream>>>((const unsigned*)h, as1, ad1, row_ptr, col, b1,
                                    hx, nullptr, N, 1);

    // ---- layer 2 ----
    gemm_mfma<<<gblocks, 256, 0, stream>>>(hx, Bg2hi, Bg2lo, h,
                                           att_s2, att_d2, as2, ad2, N);
    aggregate<<<N, 64, 0, stream>>>((const unsigned*)h, as2, ad2, row_ptr, col, b2,
                                    out, out + (size_t)N * FDIM, N, 0);
}

// Round 11
// 316.418 us; speedup vs baseline: 1.4372x; 1.4372x over previous
//
#include <hip/hip_runtime.h>
#include <hip/hip_bf16.h>
#include <hip/hip_fp16.h>

// GAT, 2 layers. N=50000, F=128, H=4, C=32, E=1.6M (+N self-loops).
// R16 (317.7us, BEST — this file is its exact restoration after R17's
// scatter experiment failed): aggregate = 1 wave = 1 node x 64 lanes,
// merged h[N][128]bf16, each edge visited once, wave-uniform col/as
// scalarized (SGPR 64). Fused weight math (R13): wgt =
// exp(leaky(as[s]+ad[node])) inline from planar a_s/a_d.
// R17 POSTMORTEM (reverted): direct global-cursor scatter wrote col in
// random 4B strides -> 16x write amplification (WRITE_SIZE 101MB for a
// 6.4MB array), 122-132us. The bucketed partition+build_bucket below is
// load-bearing FOR WRITE LOCALITY: partition streams ebuf per-bucket
// chunks; build_bucket writes col inside a 12.5KB window. Do not replace
// with global scatter. Aggregate loop body/geometry: local optimum per
// R8-R15 ledger (dedup, MLP-deepening, quarter-split all regressed).
// GEMM: split-bf16 MFMA (R5), planar logits epilogue. CSR: R3 bucketed.

#define FDIM 128
#define NHEAD 4
#define NB 512          // dst buckets for CSR build

typedef __attribute__((ext_vector_type(16))) float f32x16;
typedef __attribute__((ext_vector_type(8)))  short s16x8;

__device__ inline unsigned short f2bf(float f) {
    union { float f; unsigned u; } v; v.f = f;
    unsigned r = v.u + 0x7fff + ((v.u >> 16) & 1);   // RNE
    return (unsigned short)(r >> 16);
}
__device__ inline float2 bf2f(unsigned v) {
    union { unsigned u; float f; } a, b;
    a.u = v << 16;            // low half  = feature 2c
    b.u = v & 0xffff0000u;    // high half = feature 2c+1
    return make_float2(a.f, b.f);
}
__device__ inline void splitbf(float f, short* hi, short* lo) {
    unsigned u = __float_as_uint(f);
    float rem = f - __uint_as_float(u & 0xffff0000u);
    *hi = (short)(u >> 16);
    *lo = (short)(__float_as_uint(rem) >> 16);
}

// ---- fused: prep W1/W2 (transpose+split+swizzle) + bucket histogram ------
__global__ __launch_bounds__(256) void prep_hist(const float* __restrict__ W1,
                                                 short* __restrict__ B1hi,
                                                 short* __restrict__ B1lo,
                                                 const float* __restrict__ W2,
                                                 short* __restrict__ B2hi,
                                                 short* __restrict__ B2lo,
                                                 const int* __restrict__ dst, int E,
                                                 unsigned long long magic,
                                                 int* __restrict__ bcnt) {
    __shared__ int sh[NB];
    const int t = threadIdx.x;
    const int b = blockIdx.x;
    if (b < 128) {
        const float* W = (b < 64) ? W1 : W2;
        short* Bhi = (b < 64) ? B1hi : B2hi;
        short* Blo = (b < 64) ? B1lo : B2lo;
        int e = (b & 63) * 256 + t;   // e = k*128 + n
        int k = e >> 7, n = e & 127;
        short hi, lo;
        splitbf(W[e], &hi, &lo);
        int idx = n * 128 + (((k >> 3) ^ (n & 15)) << 3) + (k & 7);
        Bhi[idx] = hi;
        Blo[idx] = lo;
        return;
    }
    for (int i = t; i < NB; i += 256) sh[i] = 0;
    __syncthreads();
    const int stride = (gridDim.x - 128) * 256;
    for (int i = (b - 128) * 256 + t; i < E; i += stride) {
        int bk = (int)(((unsigned long long)(unsigned)dst[i] * magic) >> 40);
        atomicAdd(&sh[bk], 1);
    }
    __syncthreads();
    for (int i = t; i < NB; i += 256)
        if (sh[i]) atomicAdd(&bcnt[i], sh[i]);
}

// ---- MFMA GEMM: H[M][128](bf16) = A[M][128](f32) @ W; fused a_s/a_d -----
// a_s/a_d written PLANAR: a_s[q*M + row]
__global__ __launch_bounds__(256) void gemm_mfma(const float* __restrict__ A,
                                                 const short* __restrict__ Bghi,
                                                 const short* __restrict__ Bglo,
                                                 unsigned short* __restrict__ H,
                                                 const float* __restrict__ att_s,
                                                 const float* __restrict__ att_d,
                                                 float* __restrict__ a_s,
                                                 float* __restrict__ a_d, int M) {
    __shared__ short Bsm[2][16384];   // 64 KB: [hi/lo][n*128 + k']
    __shared__ float attsm[256];      // att_s[128], att_d[128]
    const int t = threadIdx.x;
    const int bm = blockIdx.x * 64;

    if (t < 128) attsm[t] = att_s[t];
    else         attsm[t] = att_d[t - 128];

    {   // stage B (pre-swizzled; verbatim 32KB+32KB copy)
        const uint4* ghi = (const uint4*)Bghi;
        const uint4* glo = (const uint4*)Bglo;
        uint4* shi = (uint4*)&Bsm[0][0];
        uint4* slo = (uint4*)&Bsm[1][0];
        #pragma unroll
        for (int i = 0; i < 8; i++) {
            shi[t + i * 256] = ghi[t + i * 256];
            slo[t + i * 256] = glo[t + i * 256];
        }
    }

    const int lane = t & 63;
    const int w = t >> 6;
    const int wr = w >> 1, wc = w & 1;     // wave tile: rows wr*32, cols wc*32
    const int m  = lane & 31, h2 = lane >> 5;
    const int grow = bm + wr * 32 + m;

    // A fragments: 8 k-chunks of 16; lane holds k = 16c + 8*h2 + j (j=0..7)
    s16x8 ahi[8], alo[8];
    {
        const bool ok = grow < M;
        const float* ap = A + (size_t)grow * 128 + 8 * h2;
        #pragma unroll
        for (int c = 0; c < 8; c++) {
            float ff[8];
            if (ok) {
                float4 f0 = *(const float4*)(ap + c * 16);
                float4 f1 = *(const float4*)(ap + c * 16 + 4);
                ff[0]=f0.x; ff[1]=f0.y; ff[2]=f0.z; ff[3]=f0.w;
                ff[4]=f1.x; ff[5]=f1.y; ff[6]=f1.z; ff[7]=f1.w;
            } else {
                #pragma unroll
                for (int j = 0; j < 8; j++) ff[j] = 0.f;
            }
            #pragma unroll
            for (int j = 0; j < 8; j++) {
                short hi, lo;
                splitbf(ff[j], &hi, &lo);
                ahi[c][j] = hi;
                alo[c][j] = lo;
            }
        }
    }
    __syncthreads();

    f32x16 acc[2];
    #pragma unroll
    for (int i = 0; i < 16; i++) { acc[0][i] = 0.f; acc[1][i] = 0.f; }

    #pragma unroll
    for (int ni = 0; ni < 2; ni++) {
        const int n = ni * 64 + wc * 32 + m;     // B col for this lane
        const int nbase = n * 128;
        #pragma unroll
        for (int c = 0; c < 8; c++) {
            int chunk8 = 2 * c + h2;
            int koff = ((chunk8 ^ (n & 15)) << 3);
            s16x8 bhi = *(const s16x8*)&Bsm[0][nbase + koff];
            s16x8 blo = *(const s16x8*)&Bsm[1][nbase + koff];
            acc[ni] = __builtin_amdgcn_mfma_f32_32x32x16_bf16(ahi[c], bhi, acc[ni], 0, 0, 0);
            acc[ni] = __builtin_amdgcn_mfma_f32_32x32x16_bf16(alo[c], bhi, acc[ni], 0, 0, 0);
            acc[ni] = __builtin_amdgcn_mfma_f32_32x32x16_bf16(ahi[c], blo, acc[ni], 0, 0, 0);
        }
    }

    __syncthreads();   // all waves done reading Bsm; reuse as htile
    unsigned short* htile = (unsigned short*)&Bsm[0][0];   // [64][128] bf16
    #pragma unroll
    for (int ni = 0; ni < 2; ni++) {
        const int colg = ni * 64 + wc * 32 + m;
        #pragma unroll
        for (int r = 0; r < 16; r++) {
            int row = wr * 32 + (r & 3) + 8 * (r >> 2) + 4 * h2;  // C/D m74/m101
            htile[row * 128 + colg] = (short)f2bf(acc[ni][r]);
        }
    }
    __syncthreads();

    // copy h tile out (merged [row][128]) + logits: thread = (row r, head q)
    {
        const int r = t >> 2, q = t & 3;
        const int growr = bm + r;
        if (growr < M) {
            uint4 v0 = *(uint4*)&htile[r * 128 + q * 32];
            uint4 v1 = *(uint4*)&htile[r * 128 + q * 32 + 8];
            uint4 v2 = *(uint4*)&htile[r * 128 + q * 32 + 16];
            uint4 v3 = *(uint4*)&htile[r * 128 + q * 32 + 24];
            uint4* hg = (uint4*)(H + (size_t)growr * 128);
            hg[q * 4 + 0] = v0; hg[q * 4 + 1] = v1;
            hg[q * 4 + 2] = v2; hg[q * 4 + 3] = v3;
            unsigned uu[16] = {v0.x, v0.y, v0.z, v0.w, v1.x, v1.y, v1.z, v1.w,
                               v2.x, v2.y, v2.z, v2.w, v3.x, v3.y, v3.z, v3.w};
            float ps = 0.f, pd = 0.f;
            #pragma unroll
            for (int i = 0; i < 16; i++) {
                float2 f = bf2f(uu[i]);
                ps += f.x * attsm[q * 32 + 2 * i]       + f.y * attsm[q * 32 + 2 * i + 1];
                pd += f.x * attsm[128 + q * 32 + 2 * i] + f.y * attsm[128 + q * 32 + 2 * i + 1];
            }
            a_s[(size_t)q * M + growr] = ps;     // planar [head][M]
            a_d[(size_t)q * M + growr] = pd;
        }
    }
}

// ------------------------------ CSR build ---------------------------------
__global__ __launch_bounds__(256) void bucket_scan(const int* __restrict__ bcnt,
                                                   int* __restrict__ bbase,
                                                   int* __restrict__ bcursor,
                                                   int* __restrict__ row_ptr,
                                                   int N, int E) {
    __shared__ int wsum[4];
    const int t = threadIdx.x, lane = t & 63, wid = t >> 6;
    int v0 = bcnt[2 * t], v1 = bcnt[2 * t + 1];
    int s = v0 + v1, incl = s;
    #pragma unroll
    for (int o = 1; o < 64; o <<= 1) {
        int u = __shfl_up(incl, o, 64);
        if (lane >= o) incl += u;
    }
    if (lane == 63) wsum[wid] = incl;
    __syncthreads();
    if (t == 0) {
        int a = 0;
        #pragma unroll
        for (int i = 0; i < 4; i++) { int x = wsum[i]; wsum[i] = a; a += x; }
    }
    __syncthreads();
    int excl = wsum[wid] + incl - s;
    bbase[2 * t] = excl;          bcursor[2 * t] = excl;
    bbase[2 * t + 1] = excl + v0; bcursor[2 * t + 1] = excl + v0;
    if (t == 0) { bbase[NB] = E; row_ptr[N] = E; }
}

__global__ __launch_bounds__(256) void partition(const int* __restrict__ src,
                                                 const int* __restrict__ dst, int E,
                                                 unsigned long long magic,
                                                 int* __restrict__ bcursor,
                                                 int2* __restrict__ ebuf) {
    __shared__ int shc[NB];    // per-bucket count in this block
    __shared__ int shb[NB];    // reserved global base
    __shared__ int shcur[NB];  // local cursor
    const int t = threadIdx.x;
    for (int i = t; i < NB; i += 256) shc[i] = 0;
    __syncthreads();
    const int e0 = blockIdx.x * 4096;
    int myb[16], mys[16], myd[16];
    #pragma unroll
    for (int u = 0; u < 16; u++) {
        int i = e0 + u * 256 + t;
        if (i < E) {
            mys[u] = src[i];
            myd[u] = dst[i];
            int b = (int)(((unsigned long long)(unsigned)myd[u] * magic) >> 40);
            myb[u] = b;
            atomicAdd(&shc[b], 1);
        } else myb[u] = -1;
    }
    __syncthreads();
    for (int i = t; i < NB; i += 256) {
        int c = shc[i];
        shcur[i] = 0;
        if (c) shb[i] = atomicAdd(&bcursor[i], c);
    }
    __syncthreads();
    #pragma unroll
    for (int u = 0; u < 16; u++) {
        if (myb[u] >= 0) {
            int o = atomicAdd(&shcur[myb[u]], 1);
            ebuf[shb[myb[u]] + o] = make_int2(mys[u], myd[u]);
        }
    }
}

__global__ __launch_bounds__(256) void build_bucket(const int2* __restrict__ ebuf,
                                                    const int* __restrict__ bbase,
                                                    int npb, int N,
                                                    int* __restrict__ row_ptr,
                                                    int* __restrict__ col) {
    __shared__ int degl[256];
    __shared__ int curl[256];
    const int b = blockIdx.x;
    const int t = threadIdx.x, lane = t & 63, wid = t >> 6;
    const int base = bbase[b];
    const int cnt = bbase[b + 1] - base;
    const int node0 = b * npb;
    for (int i = t; i < npb; i += 256) degl[i] = 0;
    __syncthreads();
    for (int i = t; i < cnt; i += 256) {
        int d = ebuf[base + i].y;
        atomicAdd(&degl[d - node0], 1);
    }
    __syncthreads();
    if (wid == 0) {
        int run = 0;
        for (int c = 0; c * 64 < npb; c++) {
            int idx = c * 64 + lane;
            int v = (idx < npb) ? degl[idx] : 0;
            int incl = v;
            #pragma unroll
            for (int o = 1; o < 64; o <<= 1) {
                int u = __shfl_up(incl, o, 64);
                if (lane >= o) incl += u;
            }
            int excl = incl - v + run;
            if (idx < npb) {
                curl[idx] = excl;
                int node = node0 + idx;
                if (node < N) row_ptr[node] = base + excl;
            }
            run += __shfl(incl, 63, 64);
        }
    }
    __syncthreads();
    for (int i = t; i < cnt; i += 256) {
        int2 ed = ebuf[base + i];
        int p = atomicAdd(&curl[ed.y - node0], 1);
        col[base + p] = ed.x;
    }
}

// ------------- gather aggregation: fused softmax-weighted sum per dst ------
// R16 geometry: block = 1 wave = 1 node x 64 lanes; lane li owns feats
// 2li,2li+1 of merged h[N][128]bf16 (uint gather); head hd=li>>4. Each
// edge visited ONCE. node wave-uniform -> row_ptr/col/as_h scalarized.
// R13 body: 8-chunk staged col/h/as + inline leaky+exp, scalar tail.
__global__ __launch_bounds__(64) void aggregate(const unsigned* __restrict__ h,
                                                const float* __restrict__ a_s,
                                                const float* __restrict__ a_d,
                                                const int* __restrict__ row_ptr,
                                                const int* __restrict__ col,
                                                const float* __restrict__ bias,
                                                float* __restrict__ out,
                                                float* __restrict__ out2,
                                                int n, int do_relu) {
    const int node = blockIdx.x;
    const int li = threadIdx.x;             // feature pair 2li,2li+1
    const int hd = li >> 4;                 // head (32 feats each)
    const float* __restrict__ as_h = a_s + (size_t)hd * n;
    const float adv = a_d[(size_t)hd * n + node];

    // self loop
    float e = as_h[node] + adv;
    e = fmaxf(e, 0.2f * e);
    float den = __expf(e);
    float2 hv = bf2f(h[(size_t)node * 64 + li]);
    float num0 = den * hv.x, num1 = den * hv.y;

    const int beg = row_ptr[node], end = row_ptr[node + 1];
    int j = beg;
    for (; j + 8 <= end; j += 8) {
        int s[8];
        #pragma unroll
        for (int u = 0; u < 8; u++) s[u] = col[j + u];
        unsigned v[8];
        #pragma unroll
        for (int u = 0; u < 8; u++) v[u] = h[(size_t)s[u] * 64 + li];
        float av[8];
        #pragma unroll
        for (int u = 0; u < 8; u++) av[u] = as_h[s[u]];
        #pragma unroll
        for (int u = 0; u < 8; u++) {
            float ee = av[u] + adv;
            ee = fmaxf(ee, 0.2f * ee);
            float wgt = __expf(ee);
            den += wgt;
            float2 f = bf2f(v[u]);
            num0 += wgt * f.x;
            num1 += wgt * f.y;
        }
    }
    for (; j < end; j++) {
        int s = col[j];
        float ee = as_h[s] + adv;
        ee = fmaxf(ee, 0.2f * ee);
        float wgt = __expf(ee);
        den += wgt;
        float2 f = bf2f(h[(size_t)s * 64 + li]);
        num0 += wgt * f.x;
        num1 += wgt * f.y;
    }
    float2 bv = ((const float2*)bias)[li];
    float rd = 1.0f / den;
    float o0 = num0 * rd + bv.x;
    float o1 = num1 * rd + bv.y;
    if (do_relu) { o0 = fmaxf(o0, 0.f); o1 = fmaxf(o1, 0.f); }
    ((float2*)out)[(size_t)node * 64 + li] = make_float2(o0, o1);
    if (out2) ((float2*)out2)[(size_t)node * 64 + li] = make_float2(o0, o1);
}

// ------------------------------- launcher ----------------------------------
extern "C" void kernel_launch(void* const* d_in, const int* in_sizes, int n_in,
                              void* d_out, int out_size, void* d_ws, size_t ws_size,
                              hipStream_t stream) {
    const float* x        = (const float*)d_in[0];
    const int*   edge     = (const int*)d_in[1];
    const float* W1       = (const float*)d_in[2];
    const float* att_s1   = (const float*)d_in[3];
    const float* att_d1   = (const float*)d_in[4];
    const float* b1       = (const float*)d_in[5];
    const float* W2       = (const float*)d_in[6];
    const float* att_s2   = (const float*)d_in[7];
    const float* att_d2   = (const float*)d_in[8];
    const float* b2       = (const float*)d_in[9];
    float* out = (float*)d_out;

    const int N = in_sizes[0] / FDIM;         // 50000
    const int E = in_sizes[1] / 2;            // 1600000
    const int* src = edge;
    const int* dst = edge + E;

    const int npb = (N + NB - 1) / NB;        // 98
    const unsigned long long magic = ((1ull << 40) / (unsigned long long)npb) + 1;

    char* w = (char*)d_ws;
    size_t off = 0;
    auto alloc = [&](size_t bytes) { void* p = w + off; off = (off + bytes + 255) & ~(size_t)255; return p; };
    int*   row_ptr = (int*)alloc((size_t)(N + 1) * 4);
    int*   col     = (int*)alloc((size_t)E * 4);
    int*   bcnt    = (int*)alloc((size_t)NB * 4);
    int*   bbase   = (int*)alloc((size_t)(NB + 1) * 4);
    int*   bcursor = (int*)alloc((size_t)NB * 4);
    unsigned short* h = (unsigned short*)alloc((size_t)N * FDIM * 2); // merged bf16
    float* hx      = (float*)alloc((size_t)N * FDIM * 4);   // layer-1 out; ebuf alias
    float* as1     = (float*)alloc((size_t)NHEAD * N * 4);  // planar [4][N]
    float* ad1     = (float*)alloc((size_t)NHEAD * N * 4);
    float* as2     = (float*)alloc((size_t)NHEAD * N * 4);
    float* ad2     = (float*)alloc((size_t)NHEAD * N * 4);
    short* Bg1hi   = (short*)alloc((size_t)128 * 128 * 2);
    short* Bg1lo   = (short*)alloc((size_t)128 * 128 * 2);
    short* Bg2hi   = (short*)alloc((size_t)128 * 128 * 2);
    short* Bg2lo   = (short*)alloc((size_t)128 * 128 * 2);
    int2*  ebuf    = (int2*)hx;   // dead before aggregate-1 writes hx
    (void)ws_size;

    // ---- fused weight-prep + bucket histogram ----
    hipMemsetAsync(bcnt, 0, (size_t)NB * 4, stream);
    prep_hist<<<128 + 1024, 256, 0, stream>>>(W1, Bg1hi, Bg1lo, W2, Bg2hi, Bg2lo,
                                              dst, E, magic, bcnt);
    bucket_scan<<<1, 256, 0, stream>>>(bcnt, bbase, bcursor, row_ptr, N, E);
    partition<<<(E + 4095) / 4096, 256, 0, stream>>>(src, dst, E, magic, bcursor, ebuf);
    build_bucket<<<NB, 256, 0, stream>>>(ebuf, bbase, npb, N, row_ptr, col);

    const int gblocks = (N + 63) / 64;

    // ---- layer 1 ----
    gemm_mfma<<<gblocks, 256, 0, stream>>>(x, Bg1hi, Bg1lo, h,
                                           att_s1, att_d1, as1, ad1, N);
    aggregate<<<N, 64, 0, stream>>>((const unsigned*)h, as1, ad1, row_ptr, col, b1,
                                    hx, nullptr, N, 1);

    // ---- layer 2 ----
    gemm_mfma<<<gblocks, 256, 0, stream>>>(hx, Bg2hi, Bg2lo, h,
                                           att_s2, att_d2, as2, ad2, N);
    aggregate<<<N, 64, 0, stream>>>((const unsigned*)h, as2, ad2, row_ptr, col, b2,
                                    out, out + (size_t)N * FDIM, N, 0);
}